// Round 2
// baseline (468.606 us; speedup 1.0000x reference)
//
#include <hip/hip_runtime.h>

#define IN_FEAT 256
#define OUT_FEAT 32
#define RB 64            // rows per bucket
#define CAP 1280         // edge capacity per bucket (lambda=1024, 8 sigma slack)
#define OCAP 65536       // overflow list capacity
#define CNT_STRIDE 16    // u32 stride between counters -> 64B apart (line anti-contention)

// ---------------------------------------------------------------------------
// Kernel 1: dense projection  x = feat @ W   (fp32 vector ALU; no fp32 MFMA)
//   Block 256 threads, 64 rows/block in 4 stages of 16. W staged once,
//   transposed+padded (stride 260 keeps float4 reads at <=4-way conflict).
//   Thread (rg=tid>>5, j=tid&31) computes rows rg*2, rg*2+1 of each stage.
//   LDS reads per FMA: 3 x b128 per 8 FMA = 0.375 (was 2.0 scalar).
// ---------------------------------------------------------------------------
__global__ __launch_bounds__(256) void gemm_kernel2(
    const float* __restrict__ feat,
    const float* __restrict__ W,
    float* __restrict__ x,
    int n)
{
    __shared__ float sWT[OUT_FEAT][260];   // 33.3 KB, W transposed
    __shared__ float sF[16][IN_FEAT];      // 16 KB

    const int tid = threadIdx.x;

    // Stage W transposed: sWT[j][k] = W[k*32 + j]
    for (int i = tid; i < IN_FEAT * OUT_FEAT; i += 256) {
        int k = i >> 5, j = i & 31;
        sWT[j][k] = W[i];
    }

    const int rowBase = blockIdx.x * 64;
    const int rg = tid >> 5;
    const int j  = tid & 31;
    const int rl = rg * 2;

    for (int s = 0; s < 4; ++s) {
        const int r0 = rowBase + s * 16;
        if (r0 >= n) break;               // block-uniform exit
        __syncthreads();                  // prior-stage readers done (also covers W stage)

        if (r0 + 16 <= n) {
            const float4* F4 = reinterpret_cast<const float4*>(feat + (size_t)r0 * IN_FEAT);
            float4* sF4 = reinterpret_cast<float4*>(&sF[0][0]);
            #pragma unroll
            for (int i = 0; i < 4; ++i) sF4[tid + i * 256] = F4[tid + i * 256];
        } else {
            for (int i = tid; i < 16 * IN_FEAT; i += 256) {
                int r = i >> 8, k = i & 255;
                int gr = r0 + r;
                sF[r][k] = (gr < n) ? feat[(size_t)gr * IN_FEAT + k] : 0.0f;
            }
        }
        __syncthreads();

        float acc0 = 0.0f, acc1 = 0.0f;
        #pragma unroll 8
        for (int k4 = 0; k4 < IN_FEAT / 4; ++k4) {
            float4 w  = *reinterpret_cast<const float4*>(&sWT[j][k4 * 4]);
            float4 f0 = *reinterpret_cast<const float4*>(&sF[rl][k4 * 4]);
            float4 f1 = *reinterpret_cast<const float4*>(&sF[rl + 1][k4 * 4]);
            acc0 += f0.x * w.x + f0.y * w.y + f0.z * w.z + f0.w * w.w;
            acc1 += f1.x * w.x + f1.y * w.y + f1.z * w.z + f1.w * w.w;
        }

        const int gr = r0 + rl;
        if (gr < n)     x[(size_t)gr * OUT_FEAT + j]       = acc0;
        if (gr + 1 < n) x[(size_t)(gr + 1) * OUT_FEAT + j] = acc1;
    }
}

// ---------------------------------------------------------------------------
// Kernel 2: bin edges by row bucket (row>>6).
//   pos = atomicAdd on padded per-bucket counter; packed entry
//   {key = (rlocal<<17)|col, val} (col < 2^17, rlocal < 64). Overflow (never
//   expected for this input) goes to a global list handled by oflow_kernel.
// ---------------------------------------------------------------------------
__global__ __launch_bounds__(256) void bin_kernel(
    const float* __restrict__ vals,
    const int* __restrict__ erow,
    const int* __restrict__ ecol,
    uint2* __restrict__ ebuf,
    unsigned* __restrict__ cnt,
    unsigned* __restrict__ ocnt,
    uint4* __restrict__ obuf,
    int n_edges)
{
    const int stride = gridDim.x * blockDim.x;
    for (int e = blockIdx.x * blockDim.x + threadIdx.x; e < n_edges; e += stride) {
        const int r = erow[e];
        const int c = ecol[e];
        const float v = vals[e];
        const int b = r >> 6;
        unsigned pos = atomicAdd(&cnt[(size_t)b * CNT_STRIDE], 1u);
        if (pos < CAP) {
            ebuf[(size_t)b * CAP + pos] =
                make_uint2(((unsigned)(r & 63) << 17) | (unsigned)c, __float_as_uint(v));
        } else {
            unsigned o = atomicAdd(ocnt, 1u);
            if (o < OCAP)
                obuf[o] = make_uint4((unsigned)r, (unsigned)c, __float_as_uint(v), 0u);
        }
    }
}

// ---------------------------------------------------------------------------
// Kernel 3: per-bucket SpMM. Block 512 threads = 16 edge-groups of 32 lanes.
//   LDS acc[64][32] (8 KB); lanes j=0..31 -> banks 0..31, conflict-free DS
//   atomics. 4-deep unroll for gather MLP. Non-atomic full-coverage out write
//   (so no out memset needed).
// ---------------------------------------------------------------------------
__global__ __launch_bounds__(512) void spmm_bucket_kernel(
    const uint2* __restrict__ ebuf,
    const unsigned* __restrict__ cnt,
    const float* __restrict__ x,
    float* __restrict__ out,
    int n_nodes)
{
    __shared__ float acc[RB * OUT_FEAT];   // 8 KB

    const int tid = threadIdx.x;
    const int b = blockIdx.x;

    #pragma unroll
    for (int i = 0; i < 4; ++i) acc[tid + i * 512] = 0.0f;
    __syncthreads();

    int n = (int)cnt[(size_t)b * CNT_STRIDE];
    if (n > CAP) n = CAP;
    const uint2* eb = ebuf + (size_t)b * CAP;

    const int g = tid >> 5;   // edge-group 0..15
    const int j = tid & 31;   // feature

    int i = g;
    for (; i + 48 < n; i += 64) {
        uint2 p0 = eb[i];
        uint2 p1 = eb[i + 16];
        uint2 p2 = eb[i + 32];
        uint2 p3 = eb[i + 48];
        float x0 = x[(size_t)(p0.x & 0x1FFFFu) * OUT_FEAT + j];
        float x1 = x[(size_t)(p1.x & 0x1FFFFu) * OUT_FEAT + j];
        float x2 = x[(size_t)(p2.x & 0x1FFFFu) * OUT_FEAT + j];
        float x3 = x[(size_t)(p3.x & 0x1FFFFu) * OUT_FEAT + j];
        atomicAdd(&acc[(p0.x >> 17) * OUT_FEAT + j], __uint_as_float(p0.y) * x0);
        atomicAdd(&acc[(p1.x >> 17) * OUT_FEAT + j], __uint_as_float(p1.y) * x1);
        atomicAdd(&acc[(p2.x >> 17) * OUT_FEAT + j], __uint_as_float(p2.y) * x2);
        atomicAdd(&acc[(p3.x >> 17) * OUT_FEAT + j], __uint_as_float(p3.y) * x3);
    }
    for (; i < n; i += 16) {
        uint2 p = eb[i];
        float xv = x[(size_t)(p.x & 0x1FFFFu) * OUT_FEAT + j];
        atomicAdd(&acc[(p.x >> 17) * OUT_FEAT + j], __uint_as_float(p.y) * xv);
    }
    __syncthreads();

    int nrows = n_nodes - b * RB;
    if (nrows > RB) nrows = RB;
    const int valid = nrows * OUT_FEAT;
    float4* out4 = reinterpret_cast<float4*>(out + (size_t)b * RB * OUT_FEAT);
    if (tid * 4 < valid)
        out4[tid] = *reinterpret_cast<float4*>(&acc[tid * 4]);
}

// ---------------------------------------------------------------------------
// Kernel 4: overflow cleanup (expected empty). Reads count from device memory.
// ---------------------------------------------------------------------------
__global__ __launch_bounds__(256) void oflow_kernel(
    const uint4* __restrict__ obuf,
    const unsigned* __restrict__ ocnt,
    const float* __restrict__ x,
    float* __restrict__ out)
{
    unsigned n = *ocnt;
    if (n > OCAP) n = OCAP;
    const long long total = (long long)n * OUT_FEAT;
    const long long stride = (long long)gridDim.x * blockDim.x;
    for (long long idx = blockIdx.x * (long long)blockDim.x + threadIdx.x;
         idx < total; idx += stride) {
        const int e = (int)(idx >> 5), j = (int)(idx & 31);
        uint4 p = obuf[e];
        atomicAdd(&out[(size_t)p.x * OUT_FEAT + j],
                  __uint_as_float(p.z) * x[(size_t)p.y * OUT_FEAT + j]);
    }
}

// ---------------------------------------------------------------------------
// Fallback scatter (round-1 path) if ws_size is too small for buckets.
// ---------------------------------------------------------------------------
__global__ __launch_bounds__(256) void spmm_scatter_kernel(
    const float* __restrict__ vals,
    const int* __restrict__ erow,
    const int* __restrict__ ecol,
    const float* __restrict__ x,
    float* __restrict__ out,
    int n_edges)
{
    const long long idx = (long long)blockIdx.x * blockDim.x + threadIdx.x;
    const int e = (int)(idx >> 5);
    const int j = (int)(idx & 31);
    if (e >= n_edges) return;
    const float m = vals[e] * x[(size_t)ecol[e] * OUT_FEAT + j];
    atomicAdd(&out[(size_t)erow[e] * OUT_FEAT + j], m);
}

// ---------------------------------------------------------------------------
extern "C" void kernel_launch(void* const* d_in, const int* in_sizes, int n_in,
                              void* d_out, int out_size, void* d_ws, size_t ws_size,
                              hipStream_t stream)
{
    const float* feat = (const float*)d_in[0];
    const float* W    = (const float*)d_in[1];
    const float* vals = (const float*)d_in[2];
    const int*   erow = (const int*)d_in[3];
    const int*   ecol = (const int*)d_in[4];
    float* out = (float*)d_out;

    const int n_nodes = in_sizes[0] / IN_FEAT;
    const int n_edges = in_sizes[2];
    const int NB = (n_nodes + RB - 1) / RB;

    // workspace layout (all offsets stay 16B-aligned for this problem size)
    char* ws = (char*)d_ws;
    size_t off = 0;
    float* x = (float*)(ws + off);            off += (size_t)n_nodes * OUT_FEAT * sizeof(float);
    uint2* ebuf = (uint2*)(ws + off);         off += (size_t)NB * CAP * sizeof(uint2);
    unsigned* cnt = (unsigned*)(ws + off);    size_t cnt_off = off;
                                              off += (size_t)NB * CNT_STRIDE * sizeof(unsigned);
    unsigned* ocnt = (unsigned*)(ws + off);   off += 16;
    uint4* obuf = (uint4*)(ws + off);         off += (size_t)OCAP * sizeof(uint4);
    const bool bucketed = (ws_size >= off);

    // 1) x = feat @ W
    {
        dim3 grid((n_nodes + 63) / 64);
        gemm_kernel2<<<grid, 256, 0, stream>>>(feat, W, x, n_nodes);
    }

    if (bucketed) {
        // zero bucket counters + overflow counter (contiguous region)
        size_t zlen = (size_t)NB * CNT_STRIDE * sizeof(unsigned) + 16;
        hipMemsetAsync(ws + cnt_off, 0, zlen, stream);

        // 2) bin edges by row bucket
        bin_kernel<<<1024, 256, 0, stream>>>(vals, erow, ecol, ebuf, cnt, ocnt, obuf, n_edges);

        // 3) per-bucket SpMM with LDS accumulation (writes every out row)
        spmm_bucket_kernel<<<NB, 512, 0, stream>>>(ebuf, cnt, x, out, n_nodes);

        // 4) overflow cleanup (normally zero work)
        oflow_kernel<<<64, 256, 0, stream>>>(obuf, ocnt, x, out);
    } else {
        // fallback: direct atomic scatter
        hipMemsetAsync(d_out, 0, (size_t)out_size * sizeof(float), stream);
        long long total = (long long)n_edges * OUT_FEAT;
        spmm_scatter_kernel<<<(unsigned)((total + 255) / 256), 256, 0, stream>>>(
            vals, erow, ecol, x, out, n_edges);
    }
}

// Round 3
// 338.875 us; speedup vs baseline: 1.3828x; 1.3828x over previous
//
#include <hip/hip_runtime.h>

#define IN_FEAT 256
#define OUT_FEAT 32

// ---------------------------------------------------------------------------
// Kernel 1: dense projection  x = feat @ W  (fp32 VALU; no fp32 MFMA on CDNA4)
//   Block 256 = 8 slots x 32 features; each slot handles 4 rows.
//   W staged transposed in LDS once (sWT[j][k], stride 260 keeps float4 rows
//   16B-aligned, <=4-way inherent conflict). feat read straight from global
//   as broadcast float4 (L1-coalesced, no LDS staging, no in-loop barrier).
//   Per k4 iter: 1 LDS b128 + 4 global b128 (broadcast) + 16 FMAs -> VALU-bound
//   at ~10 us; HBM floor ~16 us for the 102 MB feat read.
// ---------------------------------------------------------------------------
__global__ __launch_bounds__(256) void gemm_kernel3(
    const float* __restrict__ feat,
    const float* __restrict__ W,
    float* __restrict__ x,
    int n)
{
    __shared__ float sWT[OUT_FEAT][IN_FEAT + 4];   // stride 260 floats, 33.3 KB

    const int tid = threadIdx.x;

    // Stage W transposed: sWT[j][k] = W[k*32 + j]
    for (int i = tid; i < IN_FEAT * OUT_FEAT; i += 256) {
        int k = i >> 5, j = i & 31;
        sWT[j][k] = W[i];
    }
    __syncthreads();

    const int slot = tid >> 5;   // 0..7
    const int j    = tid & 31;   // output feature
    const int r0   = blockIdx.x * 32 + slot * 4;
    if (r0 >= n) return;

    const float4* W4row = reinterpret_cast<const float4*>(&sWT[j][0]);  // 16B-aligned (260*4*j % 16 == 0)

    if (r0 + 4 <= n) {
        const float4* f0 = reinterpret_cast<const float4*>(feat) + (size_t)r0 * (IN_FEAT / 4);
        float a0 = 0.f, a1 = 0.f, a2 = 0.f, a3 = 0.f;
        #pragma unroll 4
        for (int k4 = 0; k4 < IN_FEAT / 4; ++k4) {
            float4 w  = W4row[k4];          // LDS
            float4 v0 = f0[k4];             // global broadcast (same addr across slot lanes)
            float4 v1 = f0[64 + k4];
            float4 v2 = f0[128 + k4];
            float4 v3 = f0[192 + k4];
            a0 += v0.x * w.x + v0.y * w.y + v0.z * w.z + v0.w * w.w;
            a1 += v1.x * w.x + v1.y * w.y + v1.z * w.z + v1.w * w.w;
            a2 += v2.x * w.x + v2.y * w.y + v2.z * w.z + v2.w * w.w;
            a3 += v3.x * w.x + v3.y * w.y + v3.z * w.z + v3.w * w.w;
        }
        x[(size_t)(r0 + 0) * OUT_FEAT + j] = a0;
        x[(size_t)(r0 + 1) * OUT_FEAT + j] = a1;
        x[(size_t)(r0 + 2) * OUT_FEAT + j] = a2;
        x[(size_t)(r0 + 3) * OUT_FEAT + j] = a3;
    } else {
        // generic tail (not hit for N=100000: 100000 % 32 == 0)
        for (int r = r0; r < n && r < r0 + 4; ++r) {
            float a = 0.f;
            for (int k4 = 0; k4 < IN_FEAT / 4; ++k4) {
                float4 w = W4row[k4];
                float4 v = *reinterpret_cast<const float4*>(feat + (size_t)r * IN_FEAT + k4 * 4);
                a += v.x * w.x + v.y * w.y + v.z * w.z + v.w * w.w;
            }
            x[(size_t)r * OUT_FEAT + j] = a;
        }
    }
}

// ---------------------------------------------------------------------------
// Kernel 2: COO SpMM scatter  out[row[e]] += vals[e] * x[col[e]]
//   Exact round-1 kernel (measured 171 us, ~300G lane-atomics/s — the
//   device fp32-atomic ceiling). One lane per (edge, feature); max TLP,
//   no serial chains (round-2's bucketed walk was latency-bound at 300 us).
// ---------------------------------------------------------------------------
__global__ __launch_bounds__(256) void spmm_scatter_kernel(
    const float* __restrict__ vals,
    const int* __restrict__ erow,
    const int* __restrict__ ecol,
    const float* __restrict__ x,
    float* __restrict__ out,
    int n_edges)
{
    const long long idx = (long long)blockIdx.x * blockDim.x + threadIdx.x;
    const int e = (int)(idx >> 5);
    const int j = (int)(idx & 31);
    if (e >= n_edges) return;

    const float v = vals[e];
    const int c = ecol[e];
    const int r = erow[e];

    const float m = v * x[(size_t)c * OUT_FEAT + j];
    atomicAdd(&out[(size_t)r * OUT_FEAT + j], m);
}

// ---------------------------------------------------------------------------
extern "C" void kernel_launch(void* const* d_in, const int* in_sizes, int n_in,
                              void* d_out, int out_size, void* d_ws, size_t ws_size,
                              hipStream_t stream)
{
    const float* feat = (const float*)d_in[0];
    const float* W    = (const float*)d_in[1];
    const float* vals = (const float*)d_in[2];
    const int*   erow = (const int*)d_in[3];
    const int*   ecol = (const int*)d_in[4];
    float* out = (float*)d_out;
    float* x   = (float*)d_ws;            // [n_nodes, 32] fp32 = 12.8 MB

    const int n_nodes = in_sizes[0] / IN_FEAT;
    const int n_edges = in_sizes[2];

    // Zero the output (scatter accumulates into it).
    hipMemsetAsync(d_out, 0, (size_t)out_size * sizeof(float), stream);

    // 1) x = feat @ W
    {
        dim3 grid((n_nodes + 31) / 32);
        gemm_kernel3<<<grid, 256, 0, stream>>>(feat, W, x, n_nodes);
    }

    // 2) out = A @ x  (COO scatter with atomics)
    {
        long long total = (long long)n_edges * OUT_FEAT;
        dim3 grid((unsigned)((total + 255) / 256));
        spmm_scatter_kernel<<<grid, 256, 0, stream>>>(vals, erow, ecol, x, out, n_edges);
    }
}

// Round 4
// 198.824 us; speedup vs baseline: 2.3569x; 1.7044x over previous
//
#include <hip/hip_runtime.h>
#include <hip/hip_bf16.h>

#define IN_FEAT 256
#define OUT_FEAT 32

typedef __attribute__((ext_vector_type(8))) short short8;
typedef __attribute__((ext_vector_type(4))) float f32x4;

__device__ __forceinline__ unsigned cvt_pk_bf16(float lo, float hi) {
    unsigned r;
    asm volatile("v_cvt_pk_bf16_f32 %0, %1, %2" : "=v"(r) : "v"(lo), "v"(hi));
    return r;
}

// ---------------------------------------------------------------------------
// Kernel 1: x = feat @ W via bf16 MFMA, A-fragments straight from global.
//   One wave = one 16-row tile. Lane l reads feat[row=l&15][k=(l>>4)*8..+7]
//   as 2 float4 per k-step (32 B/lane, wave covers 2 KB/instr, fully
//   coalesced — the opposite of round-3's 32 B/instr broadcast loads).
//   In-register v_cvt_pk_bf16_f32, then mfma_f32_16x16x32_bf16 x 8 ksteps
//   x 2 col-halves. W^T staged once per block in LDS as bf16 (stride 264).
//   C/D layout (m89-verified): col=lane&15, row=(lane>>4)*4+reg.
// ---------------------------------------------------------------------------
__global__ __launch_bounds__(256) void gemm_mfma_kernel(
    const float* __restrict__ feat,
    const float* __restrict__ W,
    float* __restrict__ x,
    int n)
{
    __shared__ short sWT[OUT_FEAT][IN_FEAT + 8];   // W^T in bf16 bits, 16.5 KB

    const int tid = threadIdx.x;

    // Stage W transposed as bf16: sWT[c][k] = bf16(W[k*32+c]). One-time.
    for (int i = tid; i < IN_FEAT * OUT_FEAT; i += 256) {
        const int k = i >> 5, c = i & 31;
        __hip_bfloat16 h = __float2bfloat16(W[i]);
        sWT[c][k] = *reinterpret_cast<short*>(&h);
    }
    __syncthreads();   // before any wave may return

    const int wid  = tid >> 6;
    const int lane = tid & 63;
    const int tile = blockIdx.x * 4 + wid;
    const int row0 = tile * 16;
    if (row0 >= n) return;

    const int l16 = lane & 15;
    const int lh  = lane >> 4;          // 0..3

    if (row0 + 16 <= n) {
        // ---- MFMA fast path ----
        const int row = row0 + l16;
        const float4* fr = reinterpret_cast<const float4*>(feat) + (size_t)row * (IN_FEAT / 4);

        // Issue all 16 independent 16-B loads (8 ksteps x 32 B/lane).
        float4 ra[8][2];
        #pragma unroll
        for (int ks = 0; ks < 8; ++ks) {
            ra[ks][0] = fr[ks * 8 + lh * 2];
            ra[ks][1] = fr[ks * 8 + lh * 2 + 1];
        }

        f32x4 acc0 = {0.f, 0.f, 0.f, 0.f};
        f32x4 acc1 = {0.f, 0.f, 0.f, 0.f};

        #pragma unroll
        for (int ks = 0; ks < 8; ++ks) {
            union { short8 s; unsigned u[4]; } af;
            af.u[0] = cvt_pk_bf16(ra[ks][0].x, ra[ks][0].y);
            af.u[1] = cvt_pk_bf16(ra[ks][0].z, ra[ks][0].w);
            af.u[2] = cvt_pk_bf16(ra[ks][1].x, ra[ks][1].y);
            af.u[3] = cvt_pk_bf16(ra[ks][1].z, ra[ks][1].w);

            const int k0 = ks * 32 + lh * 8;
            short8 b0 = *reinterpret_cast<const short8*>(&sWT[l16][k0]);
            short8 b1 = *reinterpret_cast<const short8*>(&sWT[16 + l16][k0]);

            acc0 = __builtin_amdgcn_mfma_f32_16x16x32_bf16(af.s, b0, acc0, 0, 0, 0);
            acc1 = __builtin_amdgcn_mfma_f32_16x16x32_bf16(af.s, b1, acc1, 0, 0, 0);
        }

        // D: col = lane&15, row = (lane>>4)*4 + r
        #pragma unroll
        for (int r = 0; r < 4; ++r) {
            const size_t orow = (size_t)(row0 + lh * 4 + r) * OUT_FEAT;
            x[orow + l16]      = acc0[r];
            x[orow + 16 + l16] = acc1[r];
        }
    } else {
        // ---- generic tail (not hit for N=100000) ----
        const int rows = n - row0;
        for (int idx = lane; idx < rows * OUT_FEAT; idx += 64) {
            const int r = idx >> 5, j = idx & 31;
            float a = 0.f;
            for (int k = 0; k < IN_FEAT; ++k) {
                unsigned wb = ((unsigned)(unsigned short)sWT[j][k]) << 16;
                a += feat[(size_t)(row0 + r) * IN_FEAT + k] * __uint_as_float(wb);
            }
            x[(size_t)(row0 + r) * OUT_FEAT + j] = a;
        }
    }
}

// ---------------------------------------------------------------------------
// Kernel 2: COO SpMM scatter — unchanged round-1 kernel (measured 171 us,
//   ~300G lane-atomics/s device ceiling). One lane per (edge, feature).
// ---------------------------------------------------------------------------
__global__ __launch_bounds__(256) void spmm_scatter_kernel(
    const float* __restrict__ vals,
    const int* __restrict__ erow,
    const int* __restrict__ ecol,
    const float* __restrict__ x,
    float* __restrict__ out,
    int n_edges)
{
    const long long idx = (long long)blockIdx.x * blockDim.x + threadIdx.x;
    const int e = (int)(idx >> 5);
    const int j = (int)(idx & 31);
    if (e >= n_edges) return;

    const float v = vals[e];
    const int c = ecol[e];
    const int r = erow[e];

    const float m = v * x[(size_t)c * OUT_FEAT + j];
    atomicAdd(&out[(size_t)r * OUT_FEAT + j], m);
}

// ---------------------------------------------------------------------------
extern "C" void kernel_launch(void* const* d_in, const int* in_sizes, int n_in,
                              void* d_out, int out_size, void* d_ws, size_t ws_size,
                              hipStream_t stream)
{
    const float* feat = (const float*)d_in[0];
    const float* W    = (const float*)d_in[1];
    const float* vals = (const float*)d_in[2];
    const int*   erow = (const int*)d_in[3];
    const int*   ecol = (const int*)d_in[4];
    float* out = (float*)d_out;
    float* x   = (float*)d_ws;            // [n_nodes, 32] fp32 = 12.8 MB

    const int n_nodes = in_sizes[0] / IN_FEAT;
    const int n_edges = in_sizes[2];

    // Zero the output (scatter accumulates into it).
    hipMemsetAsync(d_out, 0, (size_t)out_size * sizeof(float), stream);

    // 1) x = feat @ W  (bf16 MFMA, 16 rows per wave)
    {
        const int tiles = (n_nodes + 15) / 16;
        dim3 grid((tiles + 3) / 4);
        gemm_mfma_kernel<<<grid, 256, 0, stream>>>(feat, W, x, n_nodes);
    }

    // 2) out = A @ x  (COO scatter with atomics)
    {
        long long total = (long long)n_edges * OUT_FEAT;
        dim3 grid((unsigned)((total + 255) / 256));
        spmm_scatter_kernel<<<grid, 256, 0, stream>>>(vals, erow, ecol, x, out, n_edges);
    }
}